// Round 1
// 468.703 us; speedup vs baseline: 1.0177x; 1.0177x over previous
//
#include <hip/hip_runtime.h>
#include <cstdint>
#include <cstddef>

#define TT 1000
#define NB 64000  // B*T

// ---------------------------------------------------------------------------
// NUMERICS CONTRACT (r1/r5/r6/r8-r12 verified absmax 0.0): each z[n,o] is
// ONE ascending-k fp32 fmaf chain. Do not reorder, split, or tree-reduce.
// (r4's value-exact 3-way bf16 split FAILED on summation order alone —
// reordering provably flips spikes. Order is sacred.)
//
// r13 experiment: packed fp32 FMA (v_pk_fma_f32 via f32x2 +
// __builtin_elementwise_fma). Packing is across OUTPUT COLUMNS (o-pairs) —
// each packed lane-element is an IEEE fp32 fused FMA identical to fmaf, and
// each z[n,o]'s ascending-k chain is preserved exactly. Contract intact.
// ---------------------------------------------------------------------------

typedef __attribute__((ext_vector_type(2))) float f32x2;

// async global->LDS DMA: 16B/lane; LDS dest = wave-uniform base + lane*16;
// global src per-lane.
__device__ __forceinline__ void dma16(const void* g, void* l) {
  __builtin_amdgcn_global_load_lds(
      (const __attribute__((address_space(1))) unsigned int*)g,
      (__attribute__((address_space(3))) unsigned int*)l, 16, 0, 0);
}

// ---------------------------------------------------------------------------
// A image (DMA-ready): u32 idx = (n>>7)*(K/16)*512 + kt16*512 + kd*128
//   + (n&127); byte = k&3, kd = (k>>2)&3.  16-k chunks are contiguous, so a
//   BK=32 tile = 1024 contiguous dwords (two 512 halves).
// W: plain transposed [K][Opad] f32.
// ---------------------------------------------------------------------------

// ---------------------------------------------------------------------------
// gemm_dma BK=32: 128n x 128o block, 256 thr, 8x8/thread. Double-buffered
// LDS (40 KB), ONE barrier per 32-k tile. Zero-VGPR global_load_lds staging
// for both A (u8-packed) and B. Inner product via packed f32x2 FMA.
// ---------------------------------------------------------------------------
__global__ __launch_bounds__(256) void gemm_dma(
    const unsigned int* __restrict__ Aswz, const float* __restrict__ Wt,
    float* __restrict__ Z, int KT32, int Wld, int Zld, int Ostore) {
  __shared__ unsigned int AsU[2][1024];        // 32k x 128row packed u8
  __shared__ __align__(16) float Bs[2][4096];  // 32k x 128o
  const int t = threadIdx.x;
  const int lane = t & 63;
  const int wave = t >> 6;
  const int bn = blockIdx.x * 128;
  const int bo = blockIdx.y * 128;
  const int tx4 = (t & 15) * 4;
  const int ty4 = ((t >> 4) & 15) * 4;

  // B DMA geometry: wave covers rows 2w..2w+1 (+8d per dma d)
  const int f0 = wave * 64 + lane;
  const int bk0 = f0 >> 5;
  const int bc0 = (f0 & 31) * 4;
  const float* wsrc = Wt + (size_t)bk0 * Wld + bo + bc0;
  // A DMA: 4 waves x 256 dwords = 1024 dwords (one 32-k tile)
  const unsigned int* asrc =
      Aswz + (size_t)blockIdx.x * KT32 * 1024 + wave * 256 + lane * 4;

  f32x2 acc[8][4];
#pragma unroll
  for (int j = 0; j < 8; j++)
#pragma unroll
    for (int i = 0; i < 4; i++) {
      acc[j][i][0] = 0.f;
      acc[j][i][1] = 0.f;
    }

  // prologue: stage tile 0
#pragma unroll
  for (int d = 0; d < 4; d++)
    dma16(wsrc + (size_t)(8 * d) * Wld, &Bs[0][1024 * d + wave * 256]);
  dma16(asrc, &AsU[0][wave * 256]);
  __syncthreads();

  for (int tile = 0; tile < KT32; tile++) {
    const int cur = tile & 1, nxt = cur ^ 1;
    if (tile + 1 < KT32) {  // zero-VGPR async prefetch, lands during compute
      const float* wn = wsrc + (size_t)(tile + 1) * 32 * Wld;
#pragma unroll
      for (int d = 0; d < 4; d++)
        dma16(wn + (size_t)(8 * d) * Wld, &Bs[nxt][1024 * d + wave * 256]);
      dma16(asrc + (size_t)(tile + 1) * 1024, &AsU[nxt][wave * 256]);
    }
#pragma unroll
    for (int kh = 0; kh < 2; kh++) {
#pragma unroll
      for (int kq = 0; kq < 4; kq++) {
        uint4 a0 = *(const uint4*)&AsU[cur][kh * 512 + kq * 128 + ty4];
        uint4 a1 = *(const uint4*)&AsU[cur][kh * 512 + kq * 128 + 64 + ty4];
#pragma unroll
        for (int k2 = 0; k2 < 4; k2++) {
          const int kk = kh * 16 + kq * 4 + k2;
          const int sh = k2 * 8;
          float av[8];
          av[0] = (float)((a0.x >> sh) & 0xffu);  // v_cvt_f32_ubyte
          av[1] = (float)((a0.y >> sh) & 0xffu);
          av[2] = (float)((a0.z >> sh) & 0xffu);
          av[3] = (float)((a0.w >> sh) & 0xffu);
          av[4] = (float)((a1.x >> sh) & 0xffu);
          av[5] = (float)((a1.y >> sh) & 0xffu);
          av[6] = (float)((a1.z >> sh) & 0xffu);
          av[7] = (float)((a1.w >> sh) & 0xffu);
          float4 b0 = *(const float4*)&Bs[cur][kk * 128 + tx4];
          float4 b1 = *(const float4*)&Bs[cur][kk * 128 + 64 + tx4];
          f32x2 bp[4];
          bp[0][0] = b0.x; bp[0][1] = b0.y;
          bp[1][0] = b0.z; bp[1][1] = b0.w;
          bp[2][0] = b1.x; bp[2][1] = b1.y;
          bp[3][0] = b1.z; bp[3][1] = b1.w;
#pragma unroll
          for (int j = 0; j < 8; j++) {
            f32x2 a2;
            a2[0] = av[j];
            a2[1] = av[j];
#pragma unroll
            for (int i = 0; i < 4; i++)
              acc[j][i] = __builtin_elementwise_fma(a2, bp[i], acc[j][i]);
          }
        }
      }
    }
    __syncthreads();
  }

#pragma unroll
  for (int jp = 0; jp < 2; jp++) {
#pragma unroll
    for (int j = 0; j < 4; j++) {
      int n = bn + jp * 64 + ty4 + j;
#pragma unroll
      for (int ip = 0; ip < 2; ip++) {
        int o0 = bo + ip * 64 + tx4;
        f32x2 p0 = acc[jp * 4 + j][ip * 2];
        f32x2 p1 = acc[jp * 4 + j][ip * 2 + 1];
        float* zp = Z + (size_t)n * Zld + o0;
        if (o0 + 3 < Ostore) {
          *(float4*)zp = make_float4(p0[0], p0[1], p1[0], p1[1]);
        } else {
          float aq[4] = {p0[0], p0[1], p1[0], p1[1]};
#pragma unroll
          for (int q = 0; q < 4; q++)
            if (o0 + q < Ostore) zp[q] = aq[q];
        }
      }
    }
  }
}

// ---------------------------------------------------------------------------
// gemm_l4 (r12, proven): layer 4, O=35 padded 64. 256n x 64o block, BK=16.
// Packed f32x2 FMA (same contract-safe transformation as gemm_dma).
// ---------------------------------------------------------------------------
__global__ __launch_bounds__(256) void gemm_l4(
    const unsigned int* __restrict__ Aswz, const float* __restrict__ Wt,
    float* __restrict__ Z) {
  const int KT = 16, OS = 35;
  __shared__ unsigned int Al[2][1024];
  __shared__ __align__(16) float Bl[2][1024];
  const int t = threadIdx.x;
  const int lane = t & 63;
  const int wave = t >> 6;
  const int bn = blockIdx.x * 256;
  const int h = wave >> 1;
  const int ny = (lane >> 3) * 8;
  const int ox = (lane & 7) * 8;
  const int lrow = (wave & 1) * 64 + ny;

  const unsigned int* asrc = Aswz +
      (size_t)(blockIdx.x * 2 + (wave >> 1)) * KT * 512 + (wave & 1) * 256 +
      lane * 4;
  const float* wsrc = Wt + wave * 256 + lane * 4;

  f32x2 acc[8][4];
#pragma unroll
  for (int j = 0; j < 8; j++)
#pragma unroll
    for (int i = 0; i < 4; i++) {
      acc[j][i][0] = 0.f;
      acc[j][i][1] = 0.f;
    }

  dma16(asrc, &Al[0][wave * 256]);
  dma16(wsrc, &Bl[0][wave * 256]);
  __syncthreads();

  for (int tile = 0; tile < KT; tile++) {
    const int cur = tile & 1, nxt = cur ^ 1;
    if (tile + 1 < KT) {
      dma16(asrc + (size_t)(tile + 1) * 512, &Al[nxt][wave * 256]);
      dma16(wsrc + (size_t)(tile + 1) * 1024, &Bl[nxt][wave * 256]);
    }
#pragma unroll
    for (int kq = 0; kq < 4; kq++) {
      uint4 a0 = *(const uint4*)&Al[cur][h * 512 + kq * 128 + lrow];
      uint4 a1 = *(const uint4*)&Al[cur][h * 512 + kq * 128 + lrow + 4];
#pragma unroll
      for (int k2 = 0; k2 < 4; k2++) {
        const int kk = kq * 4 + k2;
        const int sh = k2 * 8;
        float av[8];
        av[0] = (float)((a0.x >> sh) & 0xffu);
        av[1] = (float)((a0.y >> sh) & 0xffu);
        av[2] = (float)((a0.z >> sh) & 0xffu);
        av[3] = (float)((a0.w >> sh) & 0xffu);
        av[4] = (float)((a1.x >> sh) & 0xffu);
        av[5] = (float)((a1.y >> sh) & 0xffu);
        av[6] = (float)((a1.z >> sh) & 0xffu);
        av[7] = (float)((a1.w >> sh) & 0xffu);
        float4 b0 = *(const float4*)&Bl[cur][kk * 64 + ox];
        float4 b1 = *(const float4*)&Bl[cur][kk * 64 + ox + 4];
        f32x2 bp[4];
        bp[0][0] = b0.x; bp[0][1] = b0.y;
        bp[1][0] = b0.z; bp[1][1] = b0.w;
        bp[2][0] = b1.x; bp[2][1] = b1.y;
        bp[3][0] = b1.z; bp[3][1] = b1.w;
#pragma unroll
        for (int j = 0; j < 8; j++) {
          f32x2 a2;
          a2[0] = av[j];
          a2[1] = av[j];
#pragma unroll
          for (int i = 0; i < 4; i++)
            acc[j][i] = __builtin_elementwise_fma(a2, bp[i], acc[j][i]);
        }
      }
    }
    __syncthreads();
  }

#pragma unroll
  for (int j = 0; j < 8; j++) {
    int n = bn + wave * 64 + ny + j;
    float* zp = Z + (size_t)n * OS + ox;
    if (ox + 7 < OS) {
      *(float4*)zp =
          make_float4(acc[j][0][0], acc[j][0][1], acc[j][1][0], acc[j][1][1]);
      *(float4*)(zp + 4) =
          make_float4(acc[j][2][0], acc[j][2][1], acc[j][3][0], acc[j][3][1]);
    } else {
      float aq[8] = {acc[j][0][0], acc[j][0][1], acc[j][1][0], acc[j][1][1],
                     acc[j][2][0], acc[j][2][1], acc[j][3][0], acc[j][3][1]};
#pragma unroll
      for (int q = 0; q < 8; q++)
        if (ox + q < OS) zp[q] = aq[q];
    }
  }
}

// ---------------------------------------------------------------------------
// CUBA LIF recurrence (r12): depth-2 x U=25 pipeline (50 outstanding <= 63
// vmcnt cap). Exact per-step fp32 mul/add chain. Mid layers write u8 spikes
// into the A image (16-k chunk granularity).
// ---------------------------------------------------------------------------
template <bool FINAL>
__global__ __launch_bounds__(64) void cuba_kernel(
    const float* __restrict__ Z, uint8_t* __restrict__ Sout,
    float* __restrict__ Fout, unsigned int* __restrict__ cnt, int O,
    int total) {
  int gid = blockIdx.x * 64 + threadIdx.x;
  unsigned int c = 0;
  if (gid < total) {
    int b = gid / O;
    int o = gid - b * O;
    const int nb = b * TT;
    const float* zp = Z + (size_t)nb * O + o;
    float* fp = Fout + ((size_t)b * O + o) * TT;
    const int koff = (o >> 4) * 2048 + ((o >> 2) & 3) * 512 + (o & 3);
    float cur = 0.f, volt = 0.f;
    constexpr int U = 25;
    float z0[U], z1[U];

#define LOADB(buf, tbase)                         \
  _Pragma("unroll") for (int u = 0; u < U; u++) { \
    buf[u] = zp[(size_t)((tbase) + u) * O];       \
  }
#define COMPB(buf, tbase)                                              \
  _Pragma("unroll") for (int u = 0; u < U; u++) {                      \
    cur = __fadd_rn(__fmul_rn(0.75f, cur), buf[u]);                    \
    volt = __fadd_rn(__fmul_rn(0.97f, volt), cur);                     \
    bool fire = volt >= 1.25f;                                         \
    volt = fire ? 0.f : volt;                                          \
    c += fire ? 1u : 0u;                                               \
    if (FINAL) {                                                       \
      fp[(tbase) + u] = fire ? 1.f : 0.f;                              \
    } else {                                                           \
      int n = nb + (tbase) + u;                                        \
      Sout[(size_t)(n >> 7) * 32768 + koff + ((n & 127) << 2)] =       \
          (uint8_t)(fire ? 1 : 0);                                     \
    }                                                                  \
  }

    LOADB(z0, 0)
    for (int i = 0; i < 20; i++) {
      const int base = i * 2 * U;
      LOADB(z1, base + U)
      COMPB(z0, base)
      if (i < 19) LOADB(z0, base + 2 * U)
      COMPB(z1, base + U)
    }
#undef LOADB
#undef COMPB
  }
#pragma unroll
  for (int off = 32; off; off >>= 1) c += __shfl_down(c, off, 64);
  if ((threadIdx.x & 63) == 0) atomicAdd(cnt, c);
}

// ---------------------------------------------------------------------------
// Fused prep: cnt zero + input image + 4 weight transposes. (r12)
// ---------------------------------------------------------------------------
__device__ __forceinline__ void prep_w_item(const float* __restrict__ W,
                                            float* __restrict__ Wt, int O,
                                            int K, int Opad, int i) {
  int k = i / Opad, o = i - k * Opad;
  Wt[i] = (k < K && o < O) ? W[(size_t)o * K + k] : 0.f;
}

__global__ __launch_bounds__(256) void prep_all(
    const float* __restrict__ X, const float* __restrict__ W1,
    const float* __restrict__ W2, const float* __restrict__ W3,
    const float* __restrict__ W4, unsigned int* __restrict__ Ain,
    float* __restrict__ Wt1, float* __restrict__ Wt2,
    float* __restrict__ Wt3, float* __restrict__ Wt4,
    unsigned int* __restrict__ cnt) {
  const int blk = blockIdx.x;
  const int tid = threadIdx.x;
  if (blk == 0 && tid < 8) cnt[tid] = 0u;
  if (blk < 250) {
    int gid = blk * 256 + tid;  // n
    unsigned int w[8];
#pragma unroll
    for (int i = 0; i < 8; i++) w[i] = 0u;
#pragma unroll
    for (int c = 0; c < 20; c++) {
      float v = X[((size_t)(gid / TT) * 20 + c) * TT + (gid % TT)];
      w[c >> 2] |= (v != 0.f ? 1u : 0u) << ((c & 3) * 8);
    }
    // A image (K=32): idx = (n>>7)*1024 + k16*512 + kd*128 + (n&127)
    unsigned int base = (gid >> 7) * 1024 + (gid & 127);
#pragma unroll
    for (int kd8 = 0; kd8 < 8; kd8++)
      Ain[base + (kd8 >> 2) * 512 + (kd8 & 3) * 128] = w[kd8];
  } else if (blk < 282) {
    prep_w_item(W1, Wt1, 256, 20, 256, (blk - 250) * 256 + tid);
  } else if (blk < 538) {
    prep_w_item(W2, Wt2, 256, 256, 256, (blk - 282) * 256 + tid);
  } else if (blk < 794) {
    prep_w_item(W3, Wt3, 256, 256, 256, (blk - 538) * 256 + tid);
  } else {
    prep_w_item(W4, Wt4, 35, 256, 64, (blk - 794) * 256 + tid);
  }
}

__global__ void finalize_counts(const unsigned int* __restrict__ cnt,
                                float* __restrict__ out) {
  int i = threadIdx.x;
  if (i < 4) {
    const float denom[4] = {16384000.f, 16384000.f, 16384000.f, 2240000.f};
    out[i] = (float)cnt[i] / denom[i];
  }
}

// ---------------------------------------------------------------------------
extern "C" void kernel_launch(void* const* d_in, const int* in_sizes, int n_in,
                              void* d_out, int out_size, void* d_ws,
                              size_t ws_size, hipStream_t stream) {
  const float* X = (const float*)d_in[0];
  const float* W1 = (const float*)d_in[1];
  const float* W2 = (const float*)d_in[2];
  const float* W3 = (const float*)d_in[3];
  const float* W4 = (const float*)d_in[4];
  float* out = (float*)d_out;

  char* ws = (char*)d_ws;
  unsigned int* cnt = (unsigned int*)ws;                       // 256 B
  float* Z = (float*)(ws + 256);                               // 65,536,000
  unsigned int* Sa = (unsigned int*)(ws + 256 + 65536000ull);  // 16,384,000
  unsigned int* Sb = Sa + 4096000ull;                          // 16,384,000
  unsigned int* Sin = Sb + 4096000ull;                         // 2,048,000
  float* Wt1 = (float*)(Sin + 512000ull);                      // 8192 f
  float* Wt2 = Wt1 + 8192;                                     // 65536 f
  float* Wt3 = Wt2 + 65536;                                    // 65536 f
  float* Wt4 = Wt3 + 65536;                                    // 16384 f

  prep_all<<<858, 256, 0, stream>>>(X, W1, W2, W3, W4, Sin, Wt1, Wt2, Wt3,
                                    Wt4, cnt);

  dim3 gBig(500, 2);

  gemm_dma<<<gBig, 256, 0, stream>>>(Sin, Wt1, Z, 1, 256, 256, 256);
  cuba_kernel<false><<<256, 64, 0, stream>>>(Z, (uint8_t*)Sa, nullptr, cnt + 0,
                                             256, 16384);
  gemm_dma<<<gBig, 256, 0, stream>>>(Sa, Wt2, Z, 8, 256, 256, 256);
  cuba_kernel<false><<<256, 64, 0, stream>>>(Z, (uint8_t*)Sb, nullptr, cnt + 1,
                                             256, 16384);
  gemm_dma<<<gBig, 256, 0, stream>>>(Sb, Wt3, Z, 8, 256, 256, 256);
  cuba_kernel<false><<<256, 64, 0, stream>>>(Z, (uint8_t*)Sa, nullptr, cnt + 2,
                                             256, 16384);
  gemm_l4<<<250, 256, 0, stream>>>(Sa, Wt4, Z);
  cuba_kernel<true><<<35, 64, 0, stream>>>(Z, nullptr, out, cnt + 3, 35, 2240);
  finalize_counts<<<1, 64, 0, stream>>>(cnt, out + 2240000);
}